// Round 3
// baseline (1816.431 us; speedup 1.0000x reference)
//
#include <hip/hip_runtime.h>
#include <hip/hip_bf16.h>
#include <math.h>

// Fused causal attention block, fp32 end-to-end (no fp32 MFMA on CDNA4 ->
// vector-FMA implementation first; correctness before bf16 experiments).
//
// Pipeline: [1] qkv = x @ w_qkv^T (scatter to q/k/v [b][h][t][d], q pre-scaled)
//           [2] in-place RoPE on q,k (first 16 dims)
//           [3] causal flash attention -> o in [b][t][h*64+d] layout
//           [4] out = o @ w_out^T
// Workspace: 4 fp32 tensors of 6291456 elems = 96 MB.

namespace {

constexpr int B_ = 4, T_ = 2048, C_ = 768, NH_ = 12, HD_ = 64;
constexpr int BH_ = B_ * NH_;                 // 48
constexpr size_t QS_ = (size_t)BH_ * T_ * HD_; // 6291456 floats / tensor

// ---------------- generic fp32 "NT" GEMM: out[m][n] = sum_k A[m][k]*Bw[n][k]
// BM x BN x 16 tiles, 256 threads, (BM/16)x(BN/16) micro-tile per thread.
// EPI==1: scatter epilogue into q/k/v with q-scale. EPI==0: plain row-major.
template <int BM, int BN, int EPI>
__global__ __launch_bounds__(256) void sgemm_nt(
    const float* __restrict__ A, const float* __restrict__ Bw,
    float* __restrict__ out, int K, int lda, int ldb, int ldc,
    float* __restrict__ qb, float* __restrict__ kb, float* __restrict__ vb)
{
    constexpr int BK = 16;
    constexpr int TM = BM / 16, TN = BN / 16;
    __shared__ float As[BK][BM];   // k-major so fragment reads are float4
    __shared__ float Bs[BK][BN];

    const int tid = threadIdx.x;
    const int tx = tid & 15, ty = tid >> 4;
    const int m0 = blockIdx.y * BM;
    const int n0 = blockIdx.x * BN;

    float acc[TM][TN];
#pragma unroll
    for (int i = 0; i < TM; ++i)
#pragma unroll
        for (int j = 0; j < TN; ++j) acc[i][j] = 0.f;

    constexpr int nA = (BM * BK) / (256 * 4);  // float4 loads per thread
    constexpr int nB = (BN * BK) / (256 * 4);

    for (int k0 = 0; k0 < K; k0 += BK) {
#pragma unroll
        for (int a = 0; a < nA; ++a) {
            const int f = a * 256 + tid;          // float4 index in [0, BM*4)
            const int r = f >> 2, kc = (f & 3) * 4;
            const float4 vv = *(const float4*)&A[(size_t)(m0 + r) * lda + k0 + kc];
            As[kc + 0][r] = vv.x; As[kc + 1][r] = vv.y;
            As[kc + 2][r] = vv.z; As[kc + 3][r] = vv.w;
        }
#pragma unroll
        for (int a = 0; a < nB; ++a) {
            const int f = a * 256 + tid;
            const int r = f >> 2, kc = (f & 3) * 4;
            const float4 vv = *(const float4*)&Bw[(size_t)(n0 + r) * ldb + k0 + kc];
            Bs[kc + 0][r] = vv.x; Bs[kc + 1][r] = vv.y;
            Bs[kc + 2][r] = vv.z; Bs[kc + 3][r] = vv.w;
        }
        __syncthreads();
#pragma unroll 8
        for (int kk = 0; kk < BK; ++kk) {
            float av[TM], bv[TN];
#pragma unroll
            for (int i = 0; i < TM / 4; ++i)
                *(float4*)&av[i * 4] = *(const float4*)&As[kk][ty * TM + i * 4];
#pragma unroll
            for (int j = 0; j < TN / 4; ++j)
                *(float4*)&bv[j * 4] = *(const float4*)&Bs[kk][tx * TN + j * 4];
#pragma unroll
            for (int i = 0; i < TM; ++i)
#pragma unroll
                for (int j = 0; j < TN; ++j)
                    acc[i][j] = fmaf(av[i], bv[j], acc[i][j]);
        }
        __syncthreads();
    }

    if constexpr (EPI == 0) {
        (void)qb; (void)kb; (void)vb;
#pragma unroll
        for (int i = 0; i < TM; ++i) {
            const int mr = m0 + ty * TM + i;
#pragma unroll
            for (int j = 0; j < TN / 4; ++j) {
                float4 w;
                w.x = acc[i][j * 4 + 0]; w.y = acc[i][j * 4 + 1];
                w.z = acc[i][j * 4 + 2]; w.w = acc[i][j * 4 + 3];
                *(float4*)&out[(size_t)mr * ldc + n0 + tx * TN + j * 4] = w;
            }
        }
    } else {
        (void)out; (void)ldc;
#pragma unroll
        for (int i = 0; i < TM; ++i) {
            const int mr = m0 + ty * TM + i;     // row in [0, B*T)
            const int b = mr >> 11;              // T = 2048
            const int t = mr & (T_ - 1);
#pragma unroll
            for (int j = 0; j < TN / 4; ++j) {
                const int d = n0 + tx * TN + j * 4;   // col in [0, 3C); 4-aligned
                const int sec = d / C_;               // 0=q 1=k 2=v
                const int c = d - sec * C_;
                const int h = c >> 6, di = c & 63;    // same head for all 4
                float* dst = (sec == 0) ? qb : ((sec == 1) ? kb : vb);
                const float sc = (sec == 0) ? 0.125f : 1.f;  // 1/sqrt(64) folded
                float4 w;
                w.x = acc[i][j * 4 + 0] * sc; w.y = acc[i][j * 4 + 1] * sc;
                w.z = acc[i][j * 4 + 2] * sc; w.w = acc[i][j * 4 + 3] * sc;
                *(float4*)&dst[((size_t)(b * NH_ + h) * T_ + t) * HD_ + di] = w;
            }
        }
    }
}

// ---------------- in-place RoPE on q and k: pairs (i, i+8), i in [0,8)
__global__ __launch_bounds__(256) void rope_kernel(float* __restrict__ q,
                                                   float* __restrict__ k)
{
    const int g = blockIdx.x * 256 + threadIdx.x;  // 2 * BH*T * 8 threads
    const int i = g & 7;
    int row = g >> 3;
    float* buf = q;
    if (row >= BH_ * T_) { buf = k; row -= BH_ * T_; }
    const int t = row & (T_ - 1);                  // row = bh*T + t
    // freq = 10000^{-i/8} = exp(-i * ln(10000)/8)
    const float freq = __expf(-(float)i * 1.15129254649702f);
    const float a = (float)t * freq;
    const float c = cosf(a), s = sinf(a);          // libm: proper range reduction
    float* p = buf + (size_t)row * HD_;
    const float r1 = p[i], r2 = p[i + 8];
    p[i]     = r1 * c - r2 * s;
    p[i + 8] = r2 * c + r1 * s;
}

// ---------------- causal flash attention, fp32 vector
// Block: 128 threads = 128 q-rows of one (b,h). Thread owns a full q row
// (64 VGPR) + o accumulator (64 VGPR). K/V staged 64x64 in LDS; broadcast
// float4 reads. Online softmax with deferred max (rescale once per tile).
__global__ __launch_bounds__(128) void flash_kernel(
    const float* __restrict__ q, const float* __restrict__ k,
    const float* __restrict__ v, float* __restrict__ o)
{
    __shared__ float Kl[64][64];
    __shared__ float Vl[64][64];

    const int qt = (T_ / 128 - 1) - (int)blockIdx.x;  // reversed: heavy first
    const int bh = blockIdx.y;                        // 0..47
    const int tid = threadIdx.x;
    const int tq = qt * 128 + tid;                    // this thread's q row
    const size_t base = (size_t)bh * T_ * HD_;

    float4 qr[16];
    const float4* qp = (const float4*)(q + base + (size_t)tq * HD_);
#pragma unroll
    for (int i = 0; i < 16; ++i) qr[i] = qp[i];

    float4 oc[16];
#pragma unroll
    for (int i = 0; i < 16; ++i) oc[i] = make_float4(0.f, 0.f, 0.f, 0.f);
    float m = 0.f, l = 0.f;   // running (deferred) max and denom

    const int nkt = (qt + 1) * 2;                     // 64-wide k tiles needed
    for (int kt = 0; kt < nkt; ++kt) {
        __syncthreads();
#pragma unroll
        for (int it = 0; it < 8; ++it) {              // stage K and V tiles
            const int f = it * 128 + tid;             // float4 idx in [0,1024)
            const int row = f >> 4, c4 = (f & 15) * 4;
            const size_t g = base + (size_t)(kt * 64 + row) * HD_ + c4;
            ((float4*)Kl)[f] = *(const float4*)&k[g];
            ((float4*)Vl)[f] = *(const float4*)&v[g];
        }
        __syncthreads();

        float tmax = -3.0e38f;
#pragma unroll 2
        for (int j = 0; j < 64; ++j) {
            const float4* kr = (const float4*)Kl[j];
            float4 s4 = make_float4(0.f, 0.f, 0.f, 0.f);
#pragma unroll
            for (int d = 0; d < 16; ++d) {
                const float4 kv = kr[d];
                s4.x = fmaf(qr[d].x, kv.x, s4.x);
                s4.y = fmaf(qr[d].y, kv.y, s4.y);
                s4.z = fmaf(qr[d].z, kv.z, s4.z);
                s4.w = fmaf(qr[d].w, kv.w, s4.w);
            }
            const float s = (s4.x + s4.y) + (s4.z + s4.w);
            const bool valid = (kt * 64 + j) <= tq;   // causal
            const float p = valid ? __expf(s - m) : 0.f;
            if (valid) tmax = fmaxf(tmax, s);
            l += p;
            const float4* vr = (const float4*)Vl[j];
#pragma unroll
            for (int d = 0; d < 16; ++d) {
                const float4 vv = vr[d];
                oc[d].x = fmaf(p, vv.x, oc[d].x);
                oc[d].y = fmaf(p, vv.y, oc[d].y);
                oc[d].z = fmaf(p, vv.z, oc[d].z);
                oc[d].w = fmaf(p, vv.w, oc[d].w);
            }
        }
        if (tmax > m) {                               // deferred rescale
            const float f = __expf(m - tmax);
            l *= f;
#pragma unroll
            for (int d = 0; d < 16; ++d) {
                oc[d].x *= f; oc[d].y *= f; oc[d].z *= f; oc[d].w *= f;
            }
            m = tmax;
        }
    }

    const float inv = 1.f / l;
    const int b = bh / NH_, h = bh % NH_;
    float4* op = (float4*)(o + ((size_t)(b * T_ + tq)) * C_ + h * HD_);
#pragma unroll
    for (int d = 0; d < 16; ++d) {
        float4 w;
        w.x = oc[d].x * inv; w.y = oc[d].y * inv;
        w.z = oc[d].z * inv; w.w = oc[d].w * inv;
        op[d] = w;
    }
}

}  // namespace

extern "C" void kernel_launch(void* const* d_in, const int* in_sizes, int n_in,
                              void* d_out, int out_size, void* d_ws, size_t ws_size,
                              hipStream_t stream)
{
    (void)in_sizes; (void)n_in; (void)out_size; (void)ws_size;
    const float* x     = (const float*)d_in[0];   // (4,2048,768)
    const float* w_qkv = (const float*)d_in[1];   // (2304,768)
    const float* w_out = (const float*)d_in[2];   // (768,768)
    float* out = (float*)d_out;                   // (4,2048,768)

    float* q = (float*)d_ws;          // [b][h][t][d]
    float* k = q + QS_;
    float* v = k + QS_;
    float* o = v + QS_;               // [b][t][h*64+d]

    // [1] qkv projection + scatter (+ q scale). M=8192, N=2304, K=768.
    sgemm_nt<128, 128, 1><<<dim3(3 * C_ / 128, B_ * T_ / 128), 256, 0, stream>>>(
        x, w_qkv, nullptr, C_, C_, C_, 0, q, k, v);

    // [2] RoPE in place on q, k.
    rope_kernel<<<(2 * BH_ * T_ * 8) / 256, 256, 0, stream>>>(q, k);

    // [3] causal flash attention.
    flash_kernel<<<dim3(T_ / 128, BH_), 128, 0, stream>>>(q, k, v, o);

    // [4] output projection. M=8192, N=768, K=768.
    sgemm_nt<64, 128, 0><<<dim3(C_ / 128, B_ * T_ / 64), 256, 0, stream>>>(
        o, w_out, out, C_, C_, C_, C_, nullptr, nullptr, nullptr);
}

// Round 4
// 734.555 us; speedup vs baseline: 2.4728x; 2.4728x over previous
//
#include <hip/hip_runtime.h>
#include <math.h>

// Fused causal attention block.
// [1] qkv = x @ w_qkv^T  (fp32 GEMM; epilogue emits bf16 q/k [bh][t][d] with
//     q pre-scaled by 0.125, and bf16 V pre-TRANSPOSED to [bh][d][t])
// [2] RoPE in place on bf16 q,k (first 16 dims)
// [3] causal flash attention via mfma_f32_16x16x32_bf16 -> fp32 o
// [4] out = o @ w_out^T (fp32 GEMM)
// Workspace: 3x bf16 (12.6 MB each) + 1x fp32 o (25 MB) = ~63 MB.

namespace {

constexpr int B_ = 4, T_ = 2048, C_ = 768, NH_ = 12, HD_ = 64;
constexpr int BH_ = B_ * NH_;                  // 48
constexpr size_t QS_ = (size_t)BH_ * T_ * HD_; // 6291456 elems / tensor

typedef short short8 __attribute__((ext_vector_type(8)));  // 8 bf16 = 4 VGPR
typedef float f32x4 __attribute__((ext_vector_type(4)));

__device__ inline ushort f2bf(float f) {           // RNE float->bf16 bits
    unsigned u = __builtin_bit_cast(unsigned, f);
    u += 0x7fff + ((u >> 16) & 1);
    return (ushort)(u >> 16);
}
__device__ inline float bf2f(ushort h) {
    unsigned u = (unsigned)h << 16;
    return __builtin_bit_cast(float, u);
}

// ---------------- fp32 "NT" GEMM: out[m][n] = sum_k A[m][k]*Bw[n][k]
// EPI==1: epilogue scatters bf16 into q/k ([t][d]) and transposed v ([d][t]).
// EPI==0: plain fp32 row-major store.
template <int BM, int BN, int EPI>
__global__ __launch_bounds__(256) void sgemm_nt(
    const float* __restrict__ A, const float* __restrict__ Bw,
    float* __restrict__ out, int K, int lda, int ldb, int ldc,
    ushort* __restrict__ qb, ushort* __restrict__ kb, ushort* __restrict__ vb)
{
    constexpr int BK = 16;
    constexpr int TM = BM / 16, TN = BN / 16;
    __shared__ float As[BK][BM];
    __shared__ float Bs[BK][BN];

    const int tid = threadIdx.x;
    const int tx = tid & 15, ty = tid >> 4;
    const int m0 = blockIdx.y * BM;
    const int n0 = blockIdx.x * BN;

    float acc[TM][TN];
#pragma unroll
    for (int i = 0; i < TM; ++i)
#pragma unroll
        for (int j = 0; j < TN; ++j) acc[i][j] = 0.f;

    constexpr int nA = (BM * BK) / (256 * 4);
    constexpr int nB = (BN * BK) / (256 * 4);

    for (int k0 = 0; k0 < K; k0 += BK) {
#pragma unroll
        for (int a = 0; a < nA; ++a) {
            const int f = a * 256 + tid;
            const int r = f >> 2, kc = (f & 3) * 4;
            const float4 vv = *(const float4*)&A[(size_t)(m0 + r) * lda + k0 + kc];
            As[kc + 0][r] = vv.x; As[kc + 1][r] = vv.y;
            As[kc + 2][r] = vv.z; As[kc + 3][r] = vv.w;
        }
#pragma unroll
        for (int a = 0; a < nB; ++a) {
            const int f = a * 256 + tid;
            const int r = f >> 2, kc = (f & 3) * 4;
            const float4 vv = *(const float4*)&Bw[(size_t)(n0 + r) * ldb + k0 + kc];
            Bs[kc + 0][r] = vv.x; Bs[kc + 1][r] = vv.y;
            Bs[kc + 2][r] = vv.z; Bs[kc + 3][r] = vv.w;
        }
        __syncthreads();
#pragma unroll 8
        for (int kk = 0; kk < BK; ++kk) {
            float av[TM], bv[TN];
#pragma unroll
            for (int i = 0; i < TM / 4; ++i)
                *(float4*)&av[i * 4] = *(const float4*)&As[kk][ty * TM + i * 4];
#pragma unroll
            for (int j = 0; j < TN / 4; ++j)
                *(float4*)&bv[j * 4] = *(const float4*)&Bs[kk][tx * TN + j * 4];
#pragma unroll
            for (int i = 0; i < TM; ++i)
#pragma unroll
                for (int j = 0; j < TN; ++j)
                    acc[i][j] = fmaf(av[i], bv[j], acc[i][j]);
        }
        __syncthreads();
    }

    if constexpr (EPI == 0) {
        (void)qb; (void)kb; (void)vb;
#pragma unroll
        for (int i = 0; i < TM; ++i) {
            const int mr = m0 + ty * TM + i;
#pragma unroll
            for (int j = 0; j < TN / 4; ++j) {
                float4 w;
                w.x = acc[i][j * 4 + 0]; w.y = acc[i][j * 4 + 1];
                w.z = acc[i][j * 4 + 2]; w.w = acc[i][j * 4 + 3];
                *(float4*)&out[(size_t)mr * ldc + n0 + tx * TN + j * 4] = w;
            }
        }
    } else {
        (void)out; (void)ldc;
#pragma unroll
        for (int i = 0; i < TM; ++i) {
            const int mr = m0 + ty * TM + i;     // row in [0, B*T)
            const int b = mr >> 11;              // T = 2048
            const int t = mr & (T_ - 1);
#pragma unroll
            for (int j = 0; j < TN / 4; ++j) {
                const int d = n0 + tx * TN + j * 4;   // col in [0,3C); 4-aligned
                const int sec = d / C_;               // 0=q 1=k 2=v
                const int c = d - sec * C_;
                const int h = c >> 6, di = c & 63;    // same head for all 4
                if (sec == 2) {                       // V transposed [d][t]
#pragma unroll
                    for (int u = 0; u < 4; ++u)
                        vb[((size_t)(b * NH_ + h) * HD_ + di + u) * T_ + t] =
                            f2bf(acc[i][j * 4 + u]);
                } else {
                    const float sc = (sec == 0) ? 0.125f : 1.f;
                    ushort4 w4;
                    w4.x = f2bf(acc[i][j * 4 + 0] * sc);
                    w4.y = f2bf(acc[i][j * 4 + 1] * sc);
                    w4.z = f2bf(acc[i][j * 4 + 2] * sc);
                    w4.w = f2bf(acc[i][j * 4 + 3] * sc);
                    ushort* dst = ((sec == 0) ? qb : kb) +
                                  ((size_t)(b * NH_ + h) * T_ + t) * HD_ + di;
                    *(ushort4*)dst = w4;
                }
            }
        }
    }
}

// ---------------- in-place RoPE on bf16 q and k: pairs (i, i+8), i in [0,8)
__global__ __launch_bounds__(256) void rope_kernel(ushort* __restrict__ q,
                                                   ushort* __restrict__ k)
{
    const int g = blockIdx.x * 256 + threadIdx.x;
    const int i = g & 7;
    int row = g >> 3;
    ushort* buf = q;
    if (row >= BH_ * T_) { buf = k; row -= BH_ * T_; }
    const int t = row & (T_ - 1);
    const float freq = __expf(-(float)i * 1.15129254649702f);  // 10000^{-i/8}
    const float a = (float)t * freq;
    const float c = cosf(a), s = sinf(a);
    ushort* p = buf + (size_t)row * HD_;
    const float r1 = bf2f(p[i]), r2 = bf2f(p[i + 8]);
    p[i]     = f2bf(r1 * c - r2 * s);
    p[i + 8] = f2bf(r2 * c + r1 * s);
}

// ---------------- causal flash attention via bf16 MFMA.
// Block = 256 thr = 4 waves; 64 q-rows/block (16/wave); KV tiles of 64.
// LDS: K tile [64 t'][64 d], V^T tile [64 d][64 t'], P [wave][16 q][64 k'] —
// all XOR-swizzled (idx ^ ((row&7)<<3)) against 128B-row bank conflicts.
// Fragment layouts (mfma_f32_16x16x32_bf16, m89/m92-verified):
//   A: lane row = l&15, k = (l>>4)*8+[0..7]   B: lane col = l&15, same k
//   C/D: col = lane&15, row = (lane>>4)*4 + reg
__global__ __launch_bounds__(256) void flash_mfma(
    const ushort* __restrict__ q, const ushort* __restrict__ k,
    const ushort* __restrict__ v, float* __restrict__ o)
{
    __shared__ ushort Ks[64 * 64];
    __shared__ ushort Vs[64 * 64];
    __shared__ ushort Ps[4][16 * 64];

    const int qi = (T_ / 64 - 1) - (int)blockIdx.x;   // reversed: heavy first
    const int q0 = qi * 64;
    const int bh = blockIdx.y;
    const int b = bh / NH_, h = bh % NH_;
    const int tid = threadIdx.x;
    const int w = tid >> 6, l = tid & 63;
    const int lg = l >> 4, lc = l & 15;

    const size_t kvbase = (size_t)bh * T_ * HD_;   // q,k: [t][d]
    const size_t vbase  = (size_t)bh * HD_ * T_;   // v:   [d][t]

    // Q fragments (A-operand), held in registers for the whole kernel.
    short8 aq[2];
    {
        const ushort* qp = q + kvbase + (size_t)(q0 + w * 16 + lc) * HD_ + lg * 8;
        aq[0] = *(const short8*)(qp);
        aq[1] = *(const short8*)(qp + 32);
    }

    f32x4 oa[4] = {};                 // o accumulator [dc], fp32
    float m[4], lr[4];
#pragma unroll
    for (int r = 0; r < 4; ++r) { m[r] = -1e30f; lr[r] = 0.f; }

    const int nkt = qi + 1;
    for (int t0i = 0; t0i < nkt; ++t0i) {
        const int t0 = t0i * 64;
        __syncthreads();
#pragma unroll
        for (int j = 0; j < 2; ++j) {                 // stage K + V^T tiles
            const int ch = tid + j * 256;             // 512 16B chunks each
            const int row = ch >> 3, s = ch & 7;
            const int di = (row * 64 + s * 8) ^ ((row & 7) << 3);
            *(short8*)&Ks[di] =
                *(const short8*)&k[kvbase + (size_t)(t0 + row) * HD_ + s * 8];
            *(short8*)&Vs[di] =
                *(const short8*)&v[vbase + (size_t)row * T_ + t0 + s * 8];
        }
        __syncthreads();

        // S = Q K^T : 16 q-rows x 64 k-cols per wave.
        f32x4 sa[4];
#pragma unroll
        for (int kc = 0; kc < 4; ++kc) {
            const int row = kc * 16 + lc;
            const int base = row * 64;
            const int sw = (row & 7) << 3;
            short8 b0 = *(const short8*)&Ks[(base + lg * 8) ^ sw];
            short8 b1 = *(const short8*)&Ks[(base + 32 + lg * 8) ^ sw];
            f32x4 z = {0.f, 0.f, 0.f, 0.f};
            z = __builtin_amdgcn_mfma_f32_16x16x32_bf16(aq[0], b0, z, 0, 0, 0);
            z = __builtin_amdgcn_mfma_f32_16x16x32_bf16(aq[1], b1, z, 0, 0, 0);
            sa[kc] = z;
        }

        if (t0 + 63 > q0 + w * 16) {                  // causal mask (diag only)
#pragma unroll
            for (int kc = 0; kc < 4; ++kc) {
                const int kg = t0 + kc * 16 + lc;
#pragma unroll
                for (int r = 0; r < 4; ++r) {
                    const int qg = q0 + w * 16 + lg * 4 + r;
                    if (kg > qg) sa[kc][r] = -1e30f;
                }
            }
        }

        // online softmax (row stats live in the 16-lane column groups)
        float sc[4];
#pragma unroll
        for (int r = 0; r < 4; ++r) {
            float a = fmaxf(fmaxf(sa[0][r], sa[1][r]), fmaxf(sa[2][r], sa[3][r]));
            a = fmaxf(a, __shfl_xor(a, 1));
            a = fmaxf(a, __shfl_xor(a, 2));
            a = fmaxf(a, __shfl_xor(a, 4));
            a = fmaxf(a, __shfl_xor(a, 8));
            const float mn = fmaxf(m[r], a);
            sc[r] = __expf(m[r] - mn);
            m[r] = mn;
        }
#pragma unroll
        for (int r = 0; r < 4; ++r) {
            lr[r] *= sc[r];
            oa[0][r] *= sc[r]; oa[1][r] *= sc[r];
            oa[2][r] *= sc[r]; oa[3][r] *= sc[r];
        }
        float ls[4] = {0.f, 0.f, 0.f, 0.f};
#pragma unroll
        for (int kc = 0; kc < 4; ++kc) {
#pragma unroll
            for (int r = 0; r < 4; ++r) {
                const float p = __expf(sa[kc][r] - m[r]);   // masked -> 0
                ls[r] += p;
                const int qr = lg * 4 + r;
                Ps[w][(qr * 64 + kc * 16 + lc) ^ ((qr & 7) << 3)] = f2bf(p);
            }
        }
#pragma unroll
        for (int r = 0; r < 4; ++r) {
            float a = ls[r];
            a += __shfl_xor(a, 1); a += __shfl_xor(a, 2);
            a += __shfl_xor(a, 4); a += __shfl_xor(a, 8);
            lr[r] += a;
        }

        // PV: o[16 q][64 d] += P[16 q][64 k'] * V[k'][d]
        short8 pa[2];
        {
            const int sw = (lc & 7) << 3;
            pa[0] = *(const short8*)&Ps[w][(lc * 64 + lg * 8) ^ sw];
            pa[1] = *(const short8*)&Ps[w][(lc * 64 + 32 + lg * 8) ^ sw];
        }
#pragma unroll
        for (int dc = 0; dc < 4; ++dc) {
            const int row = dc * 16 + lc;
            const int base = row * 64;
            const int sw = (row & 7) << 3;
            short8 b0 = *(const short8*)&Vs[(base + lg * 8) ^ sw];
            short8 b1 = *(const short8*)&Vs[(base + 32 + lg * 8) ^ sw];
            oa[dc] = __builtin_amdgcn_mfma_f32_16x16x32_bf16(pa[0], b0, oa[dc], 0, 0, 0);
            oa[dc] = __builtin_amdgcn_mfma_f32_16x16x32_bf16(pa[1], b1, oa[dc], 0, 0, 0);
        }
    }

    // epilogue: o / l -> fp32 [b][t][h*64+d]
#pragma unroll
    for (int r = 0; r < 4; ++r) {
        const float inv = 1.f / lr[r];
        const int qg = q0 + w * 16 + lg * 4 + r;
        float* op = o + (size_t)(b * T_ + qg) * C_ + h * HD_ + lc;
#pragma unroll
        for (int dc = 0; dc < 4; ++dc) op[dc * 16] = oa[dc][r] * inv;
    }
}

}  // namespace

extern "C" void kernel_launch(void* const* d_in, const int* in_sizes, int n_in,
                              void* d_out, int out_size, void* d_ws, size_t ws_size,
                              hipStream_t stream)
{
    (void)in_sizes; (void)n_in; (void)out_size; (void)ws_size;
    const float* x     = (const float*)d_in[0];   // (4,2048,768)
    const float* w_qkv = (const float*)d_in[1];   // (2304,768)
    const float* w_out = (const float*)d_in[2];   // (768,768)
    float* out = (float*)d_out;                   // (4,2048,768)

    ushort* qb = (ushort*)d_ws;       // bf16 [bh][t][d], pre-scaled 0.125
    ushort* kb = qb + QS_;            // bf16 [bh][t][d]
    ushort* vb = kb + QS_;            // bf16 [bh][d][t]  (transposed)
    float*  ob = (float*)(vb + QS_);  // fp32 [b][t][h*64+d]

    // [1] qkv projection + bf16 scatter. M=8192, N=2304, K=768.
    sgemm_nt<128, 128, 1><<<dim3(3 * C_ / 128, B_ * T_ / 128), 256, 0, stream>>>(
        x, w_qkv, nullptr, C_, C_, C_, 0, qb, kb, vb);

    // [2] RoPE in place on q, k.
    rope_kernel<<<(2 * BH_ * T_ * 8) / 256, 256, 0, stream>>>(qb, kb);

    // [3] causal flash attention (bf16 MFMA).
    flash_mfma<<<dim3(T_ / 64, BH_), 256, 0, stream>>>(qb, kb, vb, ob);

    // [4] output projection (fp32). M=8192, N=768, K=768.
    sgemm_nt<64, 128, 0><<<dim3(C_ / 128, B_ * T_ / 64), 256, 0, stream>>>(
        ob, w_out, out, C_, C_, C_, C_, nullptr, nullptr, nullptr);
}

// Round 5
// 327.001 us; speedup vs baseline: 5.5548x; 2.2463x over previous
//
#include <hip/hip_runtime.h>
#include <math.h>

// Fused causal attention block — all matmuls on bf16 MFMA.
// [0] cvt: x, w_qkv, w_out fp32 -> bf16
// [1] qkv = x @ w_qkv^T  (MFMA GEMM; epilogue: bf16 q/k [bh][t][d], q*0.125,
//     V pre-transposed bf16 [bh][d][t])
// [2] RoPE in place on bf16 q,k (first 16 dims)
// [3] causal flash attention via mfma_f32_16x16x32_bf16 -> bf16 o
// [4] out = o @ w_out^T (MFMA GEMM, fp32 store)
// Workspace: ~68 MB.

namespace {

constexpr int B_ = 4, T_ = 2048, C_ = 768, NH_ = 12, HD_ = 64;
constexpr int BH_ = B_ * NH_;                  // 48
constexpr size_t QS_ = (size_t)BH_ * T_ * HD_; // 6291456 elems / tensor

typedef short short8 __attribute__((ext_vector_type(8)));  // 8 bf16 = 4 VGPR
typedef float f32x4 __attribute__((ext_vector_type(4)));

__device__ inline ushort f2bf(float f) {           // RNE float->bf16 bits
    unsigned u = __builtin_bit_cast(unsigned, f);
    u += 0x7fff + ((u >> 16) & 1);
    return (ushort)(u >> 16);
}
__device__ inline float bf2f(ushort h) {
    unsigned u = (unsigned)h << 16;
    return __builtin_bit_cast(float, u);
}

// ---------------- fp32 -> bf16 convert (float4 in, ushort4 out)
__global__ __launch_bounds__(256) void cvt_bf16(const float4* __restrict__ a,
                                                ushort4* __restrict__ o, int n4)
{
    const int i = blockIdx.x * 256 + threadIdx.x;
    if (i >= n4) return;
    const float4 v = a[i];
    ushort4 u;
    u.x = f2bf(v.x); u.y = f2bf(v.y); u.z = f2bf(v.z); u.w = f2bf(v.w);
    o[i] = u;
}

// ---------------- bf16 MFMA "NT" GEMM: out[m][n] = sum_k A[m][k]*Bw[n][k]
// m97 structure: 128x128 tile, BK=32, 4 waves, 4x4 f32x4 acc/wave,
// linear LDS via global_load_lds width=16, 2-barrier K-loop.
// EPI==1: scatter bf16 q/k ([t][d], q*0.125) + transposed v ([d][t]).
// EPI==0: plain fp32 row-major store (ldc = N_).
template <int EPI>
__global__ __launch_bounds__(256) void mgemm(
    const ushort* __restrict__ A, const ushort* __restrict__ Bw,
    float* __restrict__ out, int K, int N_,
    ushort* __restrict__ qb, ushort* __restrict__ kb, ushort* __restrict__ vb)
{
    constexpr int BM = 128, BN = 128, BK = 32;
    __shared__ ushort As[BM * BK];   // [128][32] row-major (k-contig)
    __shared__ ushort Bs[BN * BK];

    const int tid = threadIdx.x;
    const int w = tid >> 6, l = tid & 63;
    const int lg = l >> 4, lc = l & 15;
    const int wr = w >> 1, wc = w & 1;         // wave -> 64x64 quadrant
    const int m0 = blockIdx.y * BM;
    const int n0 = blockIdx.x * BN;

    f32x4 acc[4][4] = {};

    for (int k0 = 0; k0 < K; k0 += BK) {
        // stage A,B tiles: 512 16B-chunks each; chunk c = row (c>>2), quarter (c&3)
#pragma unroll
        for (int i = 0; i < 2; ++i) {
            const int cb = w * 128 + i * 64;   // wave-uniform chunk base
            const int c = cb + l;
            const ushort* ga = &A[(size_t)(m0 + (c >> 2)) * K + k0 + (c & 3) * 8];
            const ushort* gb = &Bw[(size_t)(n0 + (c >> 2)) * K + k0 + (c & 3) * 8];
            __builtin_amdgcn_global_load_lds(
                (const __attribute__((address_space(1))) void*)ga,
                (__attribute__((address_space(3))) void*)&As[(size_t)cb * 8], 16, 0, 0);
            __builtin_amdgcn_global_load_lds(
                (const __attribute__((address_space(1))) void*)gb,
                (__attribute__((address_space(3))) void*)&Bs[(size_t)cb * 8], 16, 0, 0);
        }
        __syncthreads();   // drains vmcnt+lgkmcnt, then barrier -> tiles ready

        short8 af[4], bf[4];
#pragma unroll
        for (int mi = 0; mi < 4; ++mi)
            af[mi] = *(const short8*)&As[(wr * 64 + mi * 16 + lc) * 32 + lg * 8];
#pragma unroll
        for (int nj = 0; nj < 4; ++nj)
            bf[nj] = *(const short8*)&Bs[(wc * 64 + nj * 16 + lc) * 32 + lg * 8];
#pragma unroll
        for (int mi = 0; mi < 4; ++mi)
#pragma unroll
            for (int nj = 0; nj < 4; ++nj)
                acc[mi][nj] = __builtin_amdgcn_mfma_f32_16x16x32_bf16(
                    af[mi], bf[nj], acc[mi][nj], 0, 0, 0);
        __syncthreads();   // reads done before next stage overwrites
    }

    // C/D layout: col = lane&15, row = (lane>>4)*4 + reg
    if constexpr (EPI == 0) {
        (void)qb; (void)kb; (void)vb;
#pragma unroll
        for (int mi = 0; mi < 4; ++mi) {
            const int m = m0 + wr * 64 + mi * 16 + lg * 4;
#pragma unroll
            for (int nj = 0; nj < 4; ++nj) {
                const int n = n0 + wc * 64 + nj * 16 + lc;
#pragma unroll
                for (int r = 0; r < 4; ++r)
                    out[(size_t)(m + r) * N_ + n] = acc[mi][nj][r];
            }
        }
    } else {
        (void)out; (void)N_;
#pragma unroll
        for (int mi = 0; mi < 4; ++mi) {
            const int m = m0 + wr * 64 + mi * 16 + lg * 4;   // row of reg 0
            const int b = m >> 11, t0 = m & (T_ - 1);        // same b for r=0..3
#pragma unroll
            for (int nj = 0; nj < 4; ++nj) {
                const int n = n0 + wc * 64 + nj * 16 + lc;   // [0, 2304)
                const int sec = n / C_;                      // 0=q 1=k 2=v
                const int cc = n - sec * C_;
                const int h = cc >> 6, di = cc & 63;
                if (sec == 2) {                              // V^T [d][t], t consec
                    ushort4 w4;
                    w4.x = f2bf(acc[mi][nj][0]); w4.y = f2bf(acc[mi][nj][1]);
                    w4.z = f2bf(acc[mi][nj][2]); w4.w = f2bf(acc[mi][nj][3]);
                    *(ushort4*)&vb[((size_t)(b * NH_ + h) * HD_ + di) * T_ + t0] = w4;
                } else {
                    ushort* dst = (sec == 0) ? qb : kb;
                    const float s = (sec == 0) ? 0.125f : 1.f;
#pragma unroll
                    for (int r = 0; r < 4; ++r)
                        dst[((size_t)(b * NH_ + h) * T_ + t0 + r) * HD_ + di] =
                            f2bf(acc[mi][nj][r] * s);
                }
            }
        }
    }
}

// ---------------- in-place RoPE on bf16 q and k: pairs (i, i+8), i in [0,8)
__global__ __launch_bounds__(256) void rope_kernel(ushort* __restrict__ q,
                                                   ushort* __restrict__ k)
{
    const int g = blockIdx.x * 256 + threadIdx.x;
    const int i = g & 7;
    int row = g >> 3;
    ushort* buf = q;
    if (row >= BH_ * T_) { buf = k; row -= BH_ * T_; }
    const int t = row & (T_ - 1);
    const float freq = __expf(-(float)i * 1.15129254649702f);  // 10000^{-i/8}
    const float a = (float)t * freq;
    const float c = cosf(a), s = sinf(a);
    ushort* p = buf + (size_t)row * HD_;
    const float r1 = bf2f(p[i]), r2 = bf2f(p[i + 8]);
    p[i]     = f2bf(r1 * c - r2 * s);
    p[i + 8] = f2bf(r2 * c + r1 * s);
}

// ---------------- causal flash attention via bf16 MFMA (unchanged from r4
// except bf16 output). Block = 4 waves; 64 q-rows; KV tiles of 64.
__global__ __launch_bounds__(256) void flash_mfma(
    const ushort* __restrict__ q, const ushort* __restrict__ k,
    const ushort* __restrict__ v, ushort* __restrict__ o)
{
    __shared__ ushort Ks[64 * 64];
    __shared__ ushort Vs[64 * 64];
    __shared__ ushort Ps[4][16 * 64];

    const int qi = (T_ / 64 - 1) - (int)blockIdx.x;   // reversed: heavy first
    const int q0 = qi * 64;
    const int bh = blockIdx.y;
    const int b = bh / NH_, h = bh % NH_;
    const int tid = threadIdx.x;
    const int w = tid >> 6, l = tid & 63;
    const int lg = l >> 4, lc = l & 15;

    const size_t kvbase = (size_t)bh * T_ * HD_;   // q,k: [t][d]
    const size_t vbase  = (size_t)bh * HD_ * T_;   // v:   [d][t]

    short8 aq[2];
    {
        const ushort* qp = q + kvbase + (size_t)(q0 + w * 16 + lc) * HD_ + lg * 8;
        aq[0] = *(const short8*)(qp);
        aq[1] = *(const short8*)(qp + 32);
    }

    f32x4 oa[4] = {};
    float m[4], lr[4];
#pragma unroll
    for (int r = 0; r < 4; ++r) { m[r] = -1e30f; lr[r] = 0.f; }

    const int nkt = qi + 1;
    for (int t0i = 0; t0i < nkt; ++t0i) {
        const int t0 = t0i * 64;
        __syncthreads();
#pragma unroll
        for (int j = 0; j < 2; ++j) {                 // stage K + V^T tiles
            const int ch = tid + j * 256;
            const int row = ch >> 3, s = ch & 7;
            const int di = (row * 64 + s * 8) ^ ((row & 7) << 3);
            *(short8*)&Ks[di] =
                *(const short8*)&k[kvbase + (size_t)(t0 + row) * HD_ + s * 8];
            *(short8*)&Vs[di] =
                *(const short8*)&v[vbase + (size_t)row * T_ + t0 + s * 8];
        }
        __syncthreads();

        f32x4 sa[4];
#pragma unroll
        for (int kc = 0; kc < 4; ++kc) {
            const int row = kc * 16 + lc;
            const int base = row * 64;
            const int sw = (row & 7) << 3;
            short8 b0 = *(const short8*)&Ks[(base + lg * 8) ^ sw];
            short8 b1 = *(const short8*)&Ks[(base + 32 + lg * 8) ^ sw];
            f32x4 z = {0.f, 0.f, 0.f, 0.f};
            z = __builtin_amdgcn_mfma_f32_16x16x32_bf16(aq[0], b0, z, 0, 0, 0);
            z = __builtin_amdgcn_mfma_f32_16x16x32_bf16(aq[1], b1, z, 0, 0, 0);
            sa[kc] = z;
        }

        if (t0 + 63 > q0 + w * 16) {                  // causal mask (diag only)
#pragma unroll
            for (int kc = 0; kc < 4; ++kc) {
                const int kg = t0 + kc * 16 + lc;
#pragma unroll
                for (int r = 0; r < 4; ++r) {
                    const int qg = q0 + w * 16 + lg * 4 + r;
                    if (kg > qg) sa[kc][r] = -1e30f;
                }
            }
        }

        float sc[4];
#pragma unroll
        for (int r = 0; r < 4; ++r) {
            float a = fmaxf(fmaxf(sa[0][r], sa[1][r]), fmaxf(sa[2][r], sa[3][r]));
            a = fmaxf(a, __shfl_xor(a, 1));
            a = fmaxf(a, __shfl_xor(a, 2));
            a = fmaxf(a, __shfl_xor(a, 4));
            a = fmaxf(a, __shfl_xor(a, 8));
            const float mn = fmaxf(m[r], a);
            sc[r] = __expf(m[r] - mn);
            m[r] = mn;
        }
#pragma unroll
        for (int r = 0; r < 4; ++r) {
            lr[r] *= sc[r];
            oa[0][r] *= sc[r]; oa[1][r] *= sc[r];
            oa[2][r] *= sc[r]; oa[3][r] *= sc[r];
        }
        float ls[4] = {0.f, 0.f, 0.f, 0.f};
#pragma unroll
        for (int kc = 0; kc < 4; ++kc) {
#pragma unroll
            for (int r = 0; r < 4; ++r) {
                const float p = __expf(sa[kc][r] - m[r]);
                ls[r] += p;
                const int qr = lg * 4 + r;
                Ps[w][(qr * 64 + kc * 16 + lc) ^ ((qr & 7) << 3)] = f2bf(p);
            }
        }
#pragma unroll
        for (int r = 0; r < 4; ++r) {
            float a = ls[r];
            a += __shfl_xor(a, 1); a += __shfl_xor(a, 2);
            a += __shfl_xor(a, 4); a += __shfl_xor(a, 8);
            lr[r] += a;
        }

        short8 pa[2];
        {
            const int sw = (lc & 7) << 3;
            pa[0] = *(const short8*)&Ps[w][(lc * 64 + lg * 8) ^ sw];
            pa[1] = *(const short8*)&Ps[w][(lc * 64 + 32 + lg * 8) ^ sw];
        }
#pragma unroll
        for (int dc = 0; dc < 4; ++dc) {
            const int row = dc * 16 + lc;
            const int base = row * 64;
            const int sw = (row & 7) << 3;
            short8 b0 = *(const short8*)&Vs[(base + lg * 8) ^ sw];
            short8 b1 = *(const short8*)&Vs[(base + 32 + lg * 8) ^ sw];
            oa[dc] = __builtin_amdgcn_mfma_f32_16x16x32_bf16(pa[0], b0, oa[dc], 0, 0, 0);
            oa[dc] = __builtin_amdgcn_mfma_f32_16x16x32_bf16(pa[1], b1, oa[dc], 0, 0, 0);
        }
    }

    // epilogue: o / l -> bf16 [b][t][h*64+d]
#pragma unroll
    for (int r = 0; r < 4; ++r) {
        const float inv = 1.f / lr[r];
        const int qg = q0 + w * 16 + lg * 4 + r;
        ushort* op = o + (size_t)(b * T_ + qg) * C_ + h * HD_ + lc;
#pragma unroll
        for (int dc = 0; dc < 4; ++dc) op[dc * 16] = f2bf(oa[dc][r] * inv);
    }
}

}  // namespace

extern "C" void kernel_launch(void* const* d_in, const int* in_sizes, int n_in,
                              void* d_out, int out_size, void* d_ws, size_t ws_size,
                              hipStream_t stream)
{
    (void)in_sizes; (void)n_in; (void)out_size; (void)ws_size;
    const float* x     = (const float*)d_in[0];   // (4,2048,768)
    const float* w_qkv = (const float*)d_in[1];   // (2304,768)
    const float* w_out = (const float*)d_in[2];   // (768,768)
    float* out = (float*)d_out;                   // (4,2048,768)

    ushort* xb    = (ushort*)d_ws;                // bf16 x [8192][768]
    ushort* wqkvb = xb + QS_;                     // bf16 [2304][768]
    ushort* woutb = wqkvb + (size_t)3 * C_ * C_;  // bf16 [768][768]
    ushort* qb    = woutb + (size_t)C_ * C_;      // bf16 [bh][t][d], *0.125
    ushort* kb    = qb + QS_;                     // bf16 [bh][t][d]
    ushort* vb    = kb + QS_;                     // bf16 [bh][d][t] (transposed)
    ushort* ob    = vb + QS_;                     // bf16 [b][t][h*64+d]

    // [0] fp32 -> bf16 converts.
    cvt_bf16<<<6144, 256, 0, stream>>>((const float4*)x, (ushort4*)xb, 1572864);
    cvt_bf16<<<1728, 256, 0, stream>>>((const float4*)w_qkv, (ushort4*)wqkvb, 442368);
    cvt_bf16<<<576, 256, 0, stream>>>((const float4*)w_out, (ushort4*)woutb, 147456);

    // [1] qkv projection (MFMA) + bf16 scatter. M=8192, N=2304, K=768.
    mgemm<1><<<dim3(18, 64), 256, 0, stream>>>(xb, wqkvb, nullptr, C_, 0, qb, kb, vb);

    // [2] RoPE in place on q, k.
    rope_kernel<<<6144, 256, 0, stream>>>(qb, kb);

    // [3] causal flash attention (bf16 MFMA).
    flash_mfma<<<dim3(T_ / 64, BH_), 256, 0, stream>>>(qb, kb, vb, ob);

    // [4] output projection (MFMA, fp32 store). M=8192, N=768, K=768.
    mgemm<0><<<dim3(6, 64), 256, 0, stream>>>(ob, woutb, out, C_, C_,
                                              nullptr, nullptr, nullptr);
}

// Round 6
// 290.623 us; speedup vs baseline: 6.2501x; 1.1252x over previous
//
#include <hip/hip_runtime.h>
#include <math.h>

// Fused causal attention block — all matmuls on bf16 MFMA.
// [0] cvt: x, w_qkv, w_out fp32 -> bf16
// [1] qkv = x @ w_qkv^T  (MFMA GEMM; epilogue: bf16 q/k [bh][t][d], q*0.125,
//     V pre-transposed bf16 [bh][d][t])
// [2] RoPE in place on bf16 q,k (first 16 dims)
// [3] causal flash attention via mfma_f32_16x16x32_bf16 -> bf16 o
//     (r6: diagonal qi swizzle for load balance, global_load_lds staging
//      with pre-swizzled source, setprio around MFMA clusters)
// [4] out = o @ w_out^T (MFMA GEMM, fp32 store)
// Workspace: ~68 MB.

namespace {

constexpr int B_ = 4, T_ = 2048, C_ = 768, NH_ = 12, HD_ = 64;
constexpr int BH_ = B_ * NH_;                  // 48
constexpr size_t QS_ = (size_t)BH_ * T_ * HD_; // 6291456 elems / tensor

typedef short short8 __attribute__((ext_vector_type(8)));  // 8 bf16 = 4 VGPR
typedef float f32x4 __attribute__((ext_vector_type(4)));

__device__ inline ushort f2bf(float f) {           // RNE float->bf16 bits
    unsigned u = __builtin_bit_cast(unsigned, f);
    u += 0x7fff + ((u >> 16) & 1);
    return (ushort)(u >> 16);
}
__device__ inline float bf2f(ushort h) {
    unsigned u = (unsigned)h << 16;
    return __builtin_bit_cast(float, u);
}

// ---------------- fp32 -> bf16 convert (float4 in, ushort4 out)
__global__ __launch_bounds__(256) void cvt_bf16(const float4* __restrict__ a,
                                                ushort4* __restrict__ o, int n4)
{
    const int i = blockIdx.x * 256 + threadIdx.x;
    if (i >= n4) return;
    const float4 v = a[i];
    ushort4 u;
    u.x = f2bf(v.x); u.y = f2bf(v.y); u.z = f2bf(v.z); u.w = f2bf(v.w);
    o[i] = u;
}

// ---------------- bf16 MFMA "NT" GEMM: out[m][n] = sum_k A[m][k]*Bw[n][k]
// m97 structure: 128x128 tile, BK=32, 4 waves, 4x4 f32x4 acc/wave,
// linear LDS via global_load_lds width=16, 2-barrier K-loop.
// EPI==1: scatter bf16 q/k ([t][d], q*0.125) + transposed v ([d][t]).
// EPI==0: plain fp32 row-major store (ldc = N_).
template <int EPI>
__global__ __launch_bounds__(256) void mgemm(
    const ushort* __restrict__ A, const ushort* __restrict__ Bw,
    float* __restrict__ out, int K, int N_,
    ushort* __restrict__ qb, ushort* __restrict__ kb, ushort* __restrict__ vb)
{
    constexpr int BM = 128, BN = 128, BK = 32;
    __shared__ ushort As[BM * BK];   // [128][32] row-major (k-contig)
    __shared__ ushort Bs[BN * BK];

    const int tid = threadIdx.x;
    const int w = tid >> 6, l = tid & 63;
    const int lg = l >> 4, lc = l & 15;
    const int wr = w >> 1, wc = w & 1;         // wave -> 64x64 quadrant
    const int m0 = blockIdx.y * BM;
    const int n0 = blockIdx.x * BN;

    f32x4 acc[4][4] = {};

    for (int k0 = 0; k0 < K; k0 += BK) {
        // stage A,B tiles: 512 16B-chunks each; chunk c = row (c>>2), quarter (c&3)
#pragma unroll
        for (int i = 0; i < 2; ++i) {
            const int cb = w * 128 + i * 64;   // wave-uniform chunk base
            const int c = cb + l;
            const ushort* ga = &A[(size_t)(m0 + (c >> 2)) * K + k0 + (c & 3) * 8];
            const ushort* gb = &Bw[(size_t)(n0 + (c >> 2)) * K + k0 + (c & 3) * 8];
            __builtin_amdgcn_global_load_lds(
                (const __attribute__((address_space(1))) void*)ga,
                (__attribute__((address_space(3))) void*)&As[(size_t)cb * 8], 16, 0, 0);
            __builtin_amdgcn_global_load_lds(
                (const __attribute__((address_space(1))) void*)gb,
                (__attribute__((address_space(3))) void*)&Bs[(size_t)cb * 8], 16, 0, 0);
        }
        __syncthreads();   // drains vmcnt+lgkmcnt, then barrier -> tiles ready

        short8 af[4], bf[4];
#pragma unroll
        for (int mi = 0; mi < 4; ++mi)
            af[mi] = *(const short8*)&As[(wr * 64 + mi * 16 + lc) * 32 + lg * 8];
#pragma unroll
        for (int nj = 0; nj < 4; ++nj)
            bf[nj] = *(const short8*)&Bs[(wc * 64 + nj * 16 + lc) * 32 + lg * 8];
#pragma unroll
        for (int mi = 0; mi < 4; ++mi)
#pragma unroll
            for (int nj = 0; nj < 4; ++nj)
                acc[mi][nj] = __builtin_amdgcn_mfma_f32_16x16x32_bf16(
                    af[mi], bf[nj], acc[mi][nj], 0, 0, 0);
        __syncthreads();   // reads done before next stage overwrites
    }

    // C/D layout: col = lane&15, row = (lane>>4)*4 + reg
    if constexpr (EPI == 0) {
        (void)qb; (void)kb; (void)vb;
#pragma unroll
        for (int mi = 0; mi < 4; ++mi) {
            const int m = m0 + wr * 64 + mi * 16 + lg * 4;
#pragma unroll
            for (int nj = 0; nj < 4; ++nj) {
                const int n = n0 + wc * 64 + nj * 16 + lc;
#pragma unroll
                for (int r = 0; r < 4; ++r)
                    out[(size_t)(m + r) * N_ + n] = acc[mi][nj][r];
            }
        }
    } else {
        (void)out; (void)N_;
#pragma unroll
        for (int mi = 0; mi < 4; ++mi) {
            const int m = m0 + wr * 64 + mi * 16 + lg * 4;   // row of reg 0
            const int b = m >> 11, t0 = m & (T_ - 1);        // same b for r=0..3
#pragma unroll
            for (int nj = 0; nj < 4; ++nj) {
                const int n = n0 + wc * 64 + nj * 16 + lc;   // [0, 2304)
                const int sec = n / C_;                      // 0=q 1=k 2=v
                const int cc = n - sec * C_;
                const int h = cc >> 6, di = cc & 63;
                if (sec == 2) {                              // V^T [d][t], t consec
                    ushort4 w4;
                    w4.x = f2bf(acc[mi][nj][0]); w4.y = f2bf(acc[mi][nj][1]);
                    w4.z = f2bf(acc[mi][nj][2]); w4.w = f2bf(acc[mi][nj][3]);
                    *(ushort4*)&vb[((size_t)(b * NH_ + h) * HD_ + di) * T_ + t0] = w4;
                } else {
                    ushort* dst = (sec == 0) ? qb : kb;
                    const float s = (sec == 0) ? 0.125f : 1.f;
#pragma unroll
                    for (int r = 0; r < 4; ++r)
                        dst[((size_t)(b * NH_ + h) * T_ + t0 + r) * HD_ + di] =
                            f2bf(acc[mi][nj][r] * s);
                }
            }
        }
    }
}

// ---------------- in-place RoPE on bf16 q and k: pairs (i, i+8), i in [0,8)
__global__ __launch_bounds__(256) void rope_kernel(ushort* __restrict__ q,
                                                   ushort* __restrict__ k)
{
    const int g = blockIdx.x * 256 + threadIdx.x;
    const int i = g & 7;
    int row = g >> 3;
    ushort* buf = q;
    if (row >= BH_ * T_) { buf = k; row -= BH_ * T_; }
    const int t = row & (T_ - 1);
    const float freq = __expf(-(float)i * 1.15129254649702f);  // 10000^{-i/8}
    const float a = (float)t * freq;
    const float c = cosf(a), s = sinf(a);
    ushort* p = buf + (size_t)row * HD_;
    const float r1 = bf2f(p[i]), r2 = bf2f(p[i + 8]);
    p[i]     = f2bf(r1 * c - r2 * s);
    p[i + 8] = f2bf(r2 * c + r1 * s);
}

// ---------------- causal flash attention via bf16 MFMA.
// Block = 4 waves; 64 q-rows; KV tiles of 64.
// r6: qi = (x+y)&31 diagonal swizzle — under any contiguous/strided
// block->CU assignment each CU sees mixed tile counts (was: all-same-qi
// resonance, 192 vs 99 mean tile-iters per CU).
// K/V staged via global_load_lds (linear LDS dest) with the XOR swizzle
// pre-applied to the GLOBAL source column (rule 21: src perm == read perm).
__global__ __launch_bounds__(256) void flash_mfma(
    const ushort* __restrict__ q, const ushort* __restrict__ k,
    const ushort* __restrict__ v, ushort* __restrict__ o)
{
    __shared__ ushort Ks[64 * 64];
    __shared__ ushort Vs[64 * 64];
    __shared__ ushort Ps[4][16 * 64];

    const int qi = ((int)blockIdx.x + (int)blockIdx.y) & 31;  // diagonal swizzle
    const int q0 = qi * 64;
    const int bh = blockIdx.y;
    const int b = bh / NH_, h = bh % NH_;
    const int tid = threadIdx.x;
    const int w = tid >> 6, l = tid & 63;
    const int lg = l >> 4, lc = l & 15;

    const size_t kvbase = (size_t)bh * T_ * HD_;   // q,k: [t][d]
    const size_t vbase  = (size_t)bh * HD_ * T_;   // v:   [d][t]

    short8 aq[2];
    {
        const ushort* qp = q + kvbase + (size_t)(q0 + w * 16 + lc) * HD_ + lg * 8;
        aq[0] = *(const short8*)(qp);
        aq[1] = *(const short8*)(qp + 32);
    }

    f32x4 oa[4] = {};
    float m[4], lr[4];
#pragma unroll
    for (int r = 0; r < 4; ++r) { m[r] = -1e30f; lr[r] = 0.f; }

    const int nkt = qi + 1;
    for (int t0i = 0; t0i < nkt; ++t0i) {
        const int t0 = t0i * 64;
        __syncthreads();                          // prev-iter reads done
        // stage K + V^T tiles: 512 16B chunks each; wave w issues 2 calls,
        // lane l covers chunk cb+l -> LDS base + l*16 (linear dest).
#pragma unroll
        for (int i = 0; i < 2; ++i) {
            const int cb = (w * 2 + i) * 64;      // wave-uniform chunk base
            const int c = cb + l;
            const int row = c >> 3, s8 = (c & 7) * 8;
            const int col = s8 ^ ((row & 7) << 3);  // pre-swizzled source col
            __builtin_amdgcn_global_load_lds(
                (const __attribute__((address_space(1))) void*)
                    &k[kvbase + (size_t)(t0 + row) * HD_ + col],
                (__attribute__((address_space(3))) void*)&Ks[cb * 8], 16, 0, 0);
            __builtin_amdgcn_global_load_lds(
                (const __attribute__((address_space(1))) void*)
                    &v[vbase + (size_t)row * T_ + t0 + col],
                (__attribute__((address_space(3))) void*)&Vs[cb * 8], 16, 0, 0);
        }
        __syncthreads();                          // vmcnt drained -> tiles ready

        f32x4 sa[4];
        __builtin_amdgcn_s_setprio(1);
#pragma unroll
        for (int kc = 0; kc < 4; ++kc) {
            const int row = kc * 16 + lc;
            const int base = row * 64;
            const int sw = (row & 7) << 3;
            short8 b0 = *(const short8*)&Ks[(base + lg * 8) ^ sw];
            short8 b1 = *(const short8*)&Ks[(base + 32 + lg * 8) ^ sw];
            f32x4 z = {0.f, 0.f, 0.f, 0.f};
            z = __builtin_amdgcn_mfma_f32_16x16x32_bf16(aq[0], b0, z, 0, 0, 0);
            z = __builtin_amdgcn_mfma_f32_16x16x32_bf16(aq[1], b1, z, 0, 0, 0);
            sa[kc] = z;
        }
        __builtin_amdgcn_s_setprio(0);

        if (t0 + 63 > q0 + w * 16) {                  // causal mask (diag only)
#pragma unroll
            for (int kc = 0; kc < 4; ++kc) {
                const int kg = t0 + kc * 16 + lc;
#pragma unroll
                for (int r = 0; r < 4; ++r) {
                    const int qg = q0 + w * 16 + lg * 4 + r;
                    if (kg > qg) sa[kc][r] = -1e30f;
                }
            }
        }

        float sc[4];
#pragma unroll
        for (int r = 0; r < 4; ++r) {
            float a = fmaxf(fmaxf(sa[0][r], sa[1][r]), fmaxf(sa[2][r], sa[3][r]));
            a = fmaxf(a, __shfl_xor(a, 1));
            a = fmaxf(a, __shfl_xor(a, 2));
            a = fmaxf(a, __shfl_xor(a, 4));
            a = fmaxf(a, __shfl_xor(a, 8));
            const float mn = fmaxf(m[r], a);
            sc[r] = __expf(m[r] - mn);
            m[r] = mn;
        }
#pragma unroll
        for (int r = 0; r < 4; ++r) {
            lr[r] *= sc[r];
            oa[0][r] *= sc[r]; oa[1][r] *= sc[r];
            oa[2][r] *= sc[r]; oa[3][r] *= sc[r];
        }
        float ls[4] = {0.f, 0.f, 0.f, 0.f};
#pragma unroll
        for (int kc = 0; kc < 4; ++kc) {
#pragma unroll
            for (int r = 0; r < 4; ++r) {
                const float p = __expf(sa[kc][r] - m[r]);
                ls[r] += p;
                const int qr = lg * 4 + r;
                Ps[w][(qr * 64 + kc * 16 + lc) ^ ((qr & 7) << 3)] = f2bf(p);
            }
        }
#pragma unroll
        for (int r = 0; r < 4; ++r) {
            float a = ls[r];
            a += __shfl_xor(a, 1); a += __shfl_xor(a, 2);
            a += __shfl_xor(a, 4); a += __shfl_xor(a, 8);
            lr[r] += a;
        }

        short8 pa[2];
        {
            const int sw = (lc & 7) << 3;
            pa[0] = *(const short8*)&Ps[w][(lc * 64 + lg * 8) ^ sw];
            pa[1] = *(const short8*)&Ps[w][(lc * 64 + 32 + lg * 8) ^ sw];
        }
        __builtin_amdgcn_s_setprio(1);
#pragma unroll
        for (int dc = 0; dc < 4; ++dc) {
            const int row = dc * 16 + lc;
            const int base = row * 64;
            const int sw = (row & 7) << 3;
            short8 b0 = *(const short8*)&Vs[(base + lg * 8) ^ sw];
            short8 b1 = *(const short8*)&Vs[(base + 32 + lg * 8) ^ sw];
            oa[dc] = __builtin_amdgcn_mfma_f32_16x16x32_bf16(pa[0], b0, oa[dc], 0, 0, 0);
            oa[dc] = __builtin_amdgcn_mfma_f32_16x16x32_bf16(pa[1], b1, oa[dc], 0, 0, 0);
        }
        __builtin_amdgcn_s_setprio(0);
    }

    // epilogue: o / l -> bf16 [b][t][h*64+d]
#pragma unroll
    for (int r = 0; r < 4; ++r) {
        const float inv = 1.f / lr[r];
        const int qg = q0 + w * 16 + lg * 4 + r;
        ushort* op = o + (size_t)(b * T_ + qg) * C_ + h * HD_ + lc;
#pragma unroll
        for (int dc = 0; dc < 4; ++dc) op[dc * 16] = f2bf(oa[dc][r] * inv);
    }
}

}  // namespace

extern "C" void kernel_launch(void* const* d_in, const int* in_sizes, int n_in,
                              void* d_out, int out_size, void* d_ws, size_t ws_size,
                              hipStream_t stream)
{
    (void)in_sizes; (void)n_in; (void)out_size; (void)ws_size;
    const float* x     = (const float*)d_in[0];   // (4,2048,768)
    const float* w_qkv = (const float*)d_in[1];   // (2304,768)
    const float* w_out = (const float*)d_in[2];   // (768,768)
    float* out = (float*)d_out;                   // (4,2048,768)

    ushort* xb    = (ushort*)d_ws;                // bf16 x [8192][768]
    ushort* wqkvb = xb + QS_;                     // bf16 [2304][768]
    ushort* woutb = wqkvb + (size_t)3 * C_ * C_;  // bf16 [768][768]
    ushort* qb    = woutb + (size_t)C_ * C_;      // bf16 [bh][t][d], *0.125
    ushort* kb    = qb + QS_;                     // bf16 [bh][t][d]
    ushort* vb    = kb + QS_;                     // bf16 [bh][d][t] (transposed)
    ushort* ob    = vb + QS_;                     // bf16 [b][t][h*64+d]

    // [0] fp32 -> bf16 converts.
    cvt_bf16<<<6144, 256, 0, stream>>>((const float4*)x, (ushort4*)xb, 1572864);
    cvt_bf16<<<1728, 256, 0, stream>>>((const float4*)w_qkv, (ushort4*)wqkvb, 442368);
    cvt_bf16<<<576, 256, 0, stream>>>((const float4*)w_out, (ushort4*)woutb, 147456);

    // [1] qkv projection (MFMA) + bf16 scatter. M=8192, N=2304, K=768.
    mgemm<1><<<dim3(18, 64), 256, 0, stream>>>(xb, wqkvb, nullptr, C_, 0, qb, kb, vb);

    // [2] RoPE in place on q, k.
    rope_kernel<<<6144, 256, 0, stream>>>(qb, kb);

    // [3] causal flash attention (bf16 MFMA).
    flash_mfma<<<dim3(T_ / 64, BH_), 256, 0, stream>>>(qb, kb, vb, ob);

    // [4] output projection (MFMA, fp32 store). M=8192, N=768, K=768.
    mgemm<0><<<dim3(6, 64), 256, 0, stream>>>(ob, woutb, out, C_, C_,
                                              nullptr, nullptr, nullptr);
}

// Round 8
// 262.114 us; speedup vs baseline: 6.9299x; 1.1088x over previous
//
#include <hip/hip_runtime.h>
#include <math.h>

// Fused causal attention block — all matmuls on bf16 MFMA.
// [0] cvt: x, w_qkv, w_out fp32 -> bf16 (single kernel)
// [1] qkv = x @ w_qkv^T  (MFMA GEMM; epilogue: bf16 q/k [bh][t][d],
//     q pre-scaled by 0.125*log2e for exp2 softmax, V^T bf16 [bh][d][t])
// [2] RoPE in place on bf16 q,k (first 16 dims)
// [3] causal flash attention via mfma_f32_16x16x32_bf16 -> bf16 o
//     r8: complement-paired q-tiles {j, 31-j} = exactly 33 tile-iters/block
//     (768 identical blocks, 3/CU, deterministic balance), double-buffered
//     K/V staging (stage(next) before compute(cur), one __syncthreads per
//     iter — semantically identical to vmcnt(0)+s_barrier here), exp2
//     softmax. vs r7: raw-asm barrier replaced by __syncthreads (de-risk).
// [4] out = o @ w_out^T (MFMA GEMM, fp32 store)

namespace {

constexpr int B_ = 4, T_ = 2048, C_ = 768, NH_ = 12, HD_ = 64;
constexpr int BH_ = B_ * NH_;                  // 48
constexpr size_t QS_ = (size_t)BH_ * T_ * HD_; // 6291456 elems / tensor

typedef short short8 __attribute__((ext_vector_type(8)));  // 8 bf16 = 4 VGPR
typedef float f32x4 __attribute__((ext_vector_type(4)));

__device__ inline ushort f2bf(float f) {           // RNE float->bf16 bits
    unsigned u = __builtin_bit_cast(unsigned, f);
    u += 0x7fff + ((u >> 16) & 1);
    return (ushort)(u >> 16);
}
__device__ inline float bf2f(ushort h) {
    unsigned u = (unsigned)h << 16;
    return __builtin_bit_cast(float, u);
}

// ---------------- fp32 -> bf16 convert, all three tensors in one launch
__global__ __launch_bounds__(256) void cvt_all(
    const float4* __restrict__ x, const float4* __restrict__ wq,
    const float4* __restrict__ wo, ushort4* __restrict__ xb,
    ushort4* __restrict__ wqb, ushort4* __restrict__ wob)
{
    int i = blockIdx.x * 256 + threadIdx.x;
    const float4* s; ushort4* d;
    if (i < 1572864) { s = x; d = xb; }
    else if (i < 2015232) { s = wq; d = wqb; i -= 1572864; }
    else { s = wo; d = wob; i -= 2015232; if (i >= 147456) return; }
    const float4 v = s[i];
    ushort4 u;
    u.x = f2bf(v.x); u.y = f2bf(v.y); u.z = f2bf(v.z); u.w = f2bf(v.w);
    d[i] = u;
}

// ---------------- bf16 MFMA "NT" GEMM: out[m][n] = sum_k A[m][k]*Bw[n][k]
// m97 structure: 128x128 tile, BK=32, 4 waves, 4x4 f32x4 acc/wave,
// linear LDS via global_load_lds width=16, 2-barrier K-loop.
template <int EPI>
__global__ __launch_bounds__(256) void mgemm(
    const ushort* __restrict__ A, const ushort* __restrict__ Bw,
    float* __restrict__ out, int K, int N_,
    ushort* __restrict__ qb, ushort* __restrict__ kb, ushort* __restrict__ vb)
{
    constexpr int BM = 128, BN = 128, BK = 32;
    __shared__ ushort As[BM * BK];   // [128][32] row-major (k-contig)
    __shared__ ushort Bs[BN * BK];

    const int tid = threadIdx.x;
    const int w = tid >> 6, l = tid & 63;
    const int lg = l >> 4, lc = l & 15;
    const int wr = w >> 1, wc = w & 1;         // wave -> 64x64 quadrant
    const int m0 = blockIdx.y * BM;
    const int n0 = blockIdx.x * BN;

    f32x4 acc[4][4] = {};

    for (int k0 = 0; k0 < K; k0 += BK) {
#pragma unroll
        for (int i = 0; i < 2; ++i) {
            const int cb = w * 128 + i * 64;   // wave-uniform chunk base
            const int c = cb + l;
            const ushort* ga = &A[(size_t)(m0 + (c >> 2)) * K + k0 + (c & 3) * 8];
            const ushort* gb = &Bw[(size_t)(n0 + (c >> 2)) * K + k0 + (c & 3) * 8];
            __builtin_amdgcn_global_load_lds(
                (const __attribute__((address_space(1))) void*)ga,
                (__attribute__((address_space(3))) void*)&As[(size_t)cb * 8], 16, 0, 0);
            __builtin_amdgcn_global_load_lds(
                (const __attribute__((address_space(1))) void*)gb,
                (__attribute__((address_space(3))) void*)&Bs[(size_t)cb * 8], 16, 0, 0);
        }
        __syncthreads();

        short8 af[4], bf[4];
#pragma unroll
        for (int mi = 0; mi < 4; ++mi)
            af[mi] = *(const short8*)&As[(wr * 64 + mi * 16 + lc) * 32 + lg * 8];
#pragma unroll
        for (int nj = 0; nj < 4; ++nj)
            bf[nj] = *(const short8*)&Bs[(wc * 64 + nj * 16 + lc) * 32 + lg * 8];
#pragma unroll
        for (int mi = 0; mi < 4; ++mi)
#pragma unroll
            for (int nj = 0; nj < 4; ++nj)
                acc[mi][nj] = __builtin_amdgcn_mfma_f32_16x16x32_bf16(
                    af[mi], bf[nj], acc[mi][nj], 0, 0, 0);
        __syncthreads();
    }

    // C/D layout: col = lane&15, row = (lane>>4)*4 + reg
    if constexpr (EPI == 0) {
        (void)qb; (void)kb; (void)vb;
#pragma unroll
        for (int mi = 0; mi < 4; ++mi) {
            const int m = m0 + wr * 64 + mi * 16 + lg * 4;
#pragma unroll
            for (int nj = 0; nj < 4; ++nj) {
                const int n = n0 + wc * 64 + nj * 16 + lc;
#pragma unroll
                for (int r = 0; r < 4; ++r)
                    out[(size_t)(m + r) * N_ + n] = acc[mi][nj][r];
            }
        }
    } else {
        (void)out; (void)N_;
#pragma unroll
        for (int mi = 0; mi < 4; ++mi) {
            const int m = m0 + wr * 64 + mi * 16 + lg * 4;   // row of reg 0
            const int b = m >> 11, t0 = m & (T_ - 1);        // same b for r=0..3
#pragma unroll
            for (int nj = 0; nj < 4; ++nj) {
                const int n = n0 + wc * 64 + nj * 16 + lc;   // [0, 2304)
                const int sec = n / C_;                      // 0=q 1=k 2=v
                const int cc = n - sec * C_;
                const int h = cc >> 6, di = cc & 63;
                if (sec == 2) {                              // V^T [d][t], t consec
                    ushort4 w4;
                    w4.x = f2bf(acc[mi][nj][0]); w4.y = f2bf(acc[mi][nj][1]);
                    w4.z = f2bf(acc[mi][nj][2]); w4.w = f2bf(acc[mi][nj][3]);
                    *(ushort4*)&vb[((size_t)(b * NH_ + h) * HD_ + di) * T_ + t0] = w4;
                } else {
                    ushort* dst = (sec == 0) ? qb : kb;
                    // q scale = 1/sqrt(64) * log2(e): exp2-softmax pre-fold
                    const float s = (sec == 0) ? 0.18033688f : 1.f;
#pragma unroll
                    for (int r = 0; r < 4; ++r)
                        dst[((size_t)(b * NH_ + h) * T_ + t0 + r) * HD_ + di] =
                            f2bf(acc[mi][nj][r] * s);
                }
            }
        }
    }
}

// ---------------- in-place RoPE on bf16 q and k: pairs (i, i+8), i in [0,8)
__global__ __launch_bounds__(256) void rope_kernel(ushort* __restrict__ q,
                                                   ushort* __restrict__ k)
{
    const int g = blockIdx.x * 256 + threadIdx.x;
    const int i = g & 7;
    int row = g >> 3;
    ushort* buf = q;
    if (row >= BH_ * T_) { buf = k; row -= BH_ * T_; }
    const int t = row & (T_ - 1);
    const float freq = __expf(-(float)i * 1.15129254649702f);  // 10000^{-i/8}
    const float a = (float)t * freq;
    const float c = cosf(a), s = sinf(a);
    ushort* p = buf + (size_t)row * HD_;
    const float r1 = bf2f(p[i]), r2 = bf2f(p[i + 8]);
    p[i]     = f2bf(r1 * c - r2 * s);
    p[i + 8] = f2bf(r2 * c + r1 * s);
}

// ---------------- causal flash attention via bf16 MFMA.
// Block = 4 waves, handles q-tiles {j, 31-j}: 33 tile-iters for EVERY block.
// Grid (16, 48) = 768 blocks = 3/CU, all resident, perfect static balance.
// K/V double-buffered: stage(next) issued right after the barrier, so the
// loads overlap the whole compute phase; next iteration's __syncthreads
// (= s_waitcnt vmcnt(0) lgkmcnt(0); s_barrier) guarantees landing.
__global__ __launch_bounds__(256) void flash_mfma(
    const ushort* __restrict__ q, const ushort* __restrict__ k,
    const ushort* __restrict__ v, ushort* __restrict__ o)
{
    __shared__ ushort Ks[2][64 * 64];
    __shared__ ushort Vs[2][64 * 64];
    __shared__ ushort Ps[4][16 * 64];

    const int j = blockIdx.x;                     // 0..15
    const int bh = blockIdx.y;
    const int b = bh / NH_, h = bh % NH_;
    const int tid = threadIdx.x;
    const int w = tid >> 6, l = tid & 63;
    const int lg = l >> 4, lc = l & 15;

    const size_t kvbase = (size_t)bh * T_ * HD_;   // q,k: [t][d]
    const size_t vbase  = (size_t)bh * HD_ * T_;   // v:   [d][t]

    // stage K+V tile t0 into buffer buf: 512 16B chunks each, linear LDS
    // dest, XOR swizzle pre-applied to the GLOBAL source column (rule 21).
    auto stage = [&](int buf, int t0) {
#pragma unroll
        for (int i = 0; i < 2; ++i) {
            const int cb = (w * 2 + i) * 64;      // wave-uniform chunk base
            const int c = cb + l;
            const int row = c >> 3, s8 = (c & 7) * 8;
            const int col = s8 ^ ((row & 7) << 3);
            __builtin_amdgcn_global_load_lds(
                (const __attribute__((address_space(1))) void*)
                    &k[kvbase + (size_t)(t0 + row) * HD_ + col],
                (__attribute__((address_space(3))) void*)&Ks[buf][cb * 8], 16, 0, 0);
            __builtin_amdgcn_global_load_lds(
                (const __attribute__((address_space(1))) void*)
                    &v[vbase + (size_t)row * T_ + t0 + col],
                (__attribute__((address_space(3))) void*)&Vs[buf][cb * 8], 16, 0, 0);
        }
    };

    int cur = 0;
    stage(0, 0);                                   // prologue: seg0 tile0

    for (int seg = 0; seg < 2; ++seg) {
        const int qi = seg ? (31 - j) : j;
        const int q0 = qi * 64;

        short8 aq[2];
        {
            const ushort* qp =
                q + kvbase + (size_t)(q0 + w * 16 + lc) * HD_ + lg * 8;
            aq[0] = *(const short8*)(qp);
            aq[1] = *(const short8*)(qp + 32);
        }
        f32x4 oa[4] = {};
        float m[4], lr[4];
#pragma unroll
        for (int r = 0; r < 4; ++r) { m[r] = -1e30f; lr[r] = 0.f; }

        const int nkt = qi + 1;
        for (int t0i = 0; t0i < nkt; ++t0i) {
            const int t0 = t0i * 64;
            // all waves' prefetch for buffer cur landed (vmcnt drain) AND
            // all reads of buffer cur^1 finished (data-dependency before
            // barrier) -> safe to compute cur and re-stage cur^1.
            __syncthreads();
            const bool lastAll = (seg == 1) && (t0i == nkt - 1);
            if (!lastAll) {
                const int nt0 = (t0i + 1 < nkt) ? (t0 + 64) : 0;  // next seg wraps
                stage(cur ^ 1, nt0);
            }

            f32x4 sa[4];
            __builtin_amdgcn_s_setprio(1);
#pragma unroll
            for (int kc = 0; kc < 4; ++kc) {
                const int row = kc * 16 + lc;
                const int base = row * 64;
                const int sw = (row & 7) << 3;
                short8 b0 = *(const short8*)&Ks[cur][(base + lg * 8) ^ sw];
                short8 b1 = *(const short8*)&Ks[cur][(base + 32 + lg * 8) ^ sw];
                f32x4 z = {0.f, 0.f, 0.f, 0.f};
                z = __builtin_amdgcn_mfma_f32_16x16x32_bf16(aq[0], b0, z, 0, 0, 0);
                z = __builtin_amdgcn_mfma_f32_16x16x32_bf16(aq[1], b1, z, 0, 0, 0);
                sa[kc] = z;
            }
            __builtin_amdgcn_s_setprio(0);

            if (t0 + 63 > q0 + w * 16) {              // causal mask (diag only)
#pragma unroll
                for (int kc = 0; kc < 4; ++kc) {
                    const int kg = t0 + kc * 16 + lc;
#pragma unroll
                    for (int r = 0; r < 4; ++r) {
                        const int qg = q0 + w * 16 + lg * 4 + r;
                        if (kg > qg) sa[kc][r] = -1e30f;
                    }
                }
            }

            float sc[4];
#pragma unroll
            for (int r = 0; r < 4; ++r) {
                float a = fmaxf(fmaxf(sa[0][r], sa[1][r]),
                                fmaxf(sa[2][r], sa[3][r]));
                a = fmaxf(a, __shfl_xor(a, 1));
                a = fmaxf(a, __shfl_xor(a, 2));
                a = fmaxf(a, __shfl_xor(a, 4));
                a = fmaxf(a, __shfl_xor(a, 8));
                const float mn = fmaxf(m[r], a);
                sc[r] = exp2f(m[r] - mn);
                m[r] = mn;
            }
#pragma unroll
            for (int r = 0; r < 4; ++r) {
                lr[r] *= sc[r];
                oa[0][r] *= sc[r]; oa[1][r] *= sc[r];
                oa[2][r] *= sc[r]; oa[3][r] *= sc[r];
            }
            float ls[4] = {0.f, 0.f, 0.f, 0.f};
#pragma unroll
            for (int kc = 0; kc < 4; ++kc) {
#pragma unroll
                for (int r = 0; r < 4; ++r) {
                    const float p = exp2f(sa[kc][r] - m[r]);   // masked -> 0
                    ls[r] += p;
                    const int qr = lg * 4 + r;
                    Ps[w][(qr * 64 + kc * 16 + lc) ^ ((qr & 7) << 3)] = f2bf(p);
                }
            }
#pragma unroll
            for (int r = 0; r < 4; ++r) {
                float a = ls[r];
                a += __shfl_xor(a, 1); a += __shfl_xor(a, 2);
                a += __shfl_xor(a, 4); a += __shfl_xor(a, 8);
                lr[r] += a;
            }

            short8 pa[2];
            {
                const int sw = (lc & 7) << 3;
                pa[0] = *(const short8*)&Ps[w][(lc * 64 + lg * 8) ^ sw];
                pa[1] = *(const short8*)&Ps[w][(lc * 64 + 32 + lg * 8) ^ sw];
            }
            __builtin_amdgcn_s_setprio(1);
#pragma unroll
            for (int dc = 0; dc < 4; ++dc) {
                const int row = dc * 16 + lc;
                const int base = row * 64;
                const int sw = (row & 7) << 3;
                short8 b0 = *(const short8*)&Vs[cur][(base + lg * 8) ^ sw];
                short8 b1 = *(const short8*)&Vs[cur][(base + 32 + lg * 8) ^ sw];
                oa[dc] = __builtin_amdgcn_mfma_f32_16x16x32_bf16(pa[0], b0, oa[dc], 0, 0, 0);
                oa[dc] = __builtin_amdgcn_mfma_f32_16x16x32_bf16(pa[1], b1, oa[dc], 0, 0, 0);
            }
            __builtin_amdgcn_s_setprio(0);
            cur ^= 1;
        }

        // epilogue: o / l -> bf16 [b][t][h*64+d]
#pragma unroll
        for (int r = 0; r < 4; ++r) {
            const float inv = 1.f / lr[r];
            const int qg = q0 + w * 16 + lg * 4 + r;
            ushort* op = o + (size_t)(b * T_ + qg) * C_ + h * HD_ + lc;
#pragma unroll
            for (int dc = 0; dc < 4; ++dc) op[dc * 16] = f2bf(oa[dc][r] * inv);
        }
    }
}

}  // namespace

extern "C" void kernel_launch(void* const* d_in, const int* in_sizes, int n_in,
                              void* d_out, int out_size, void* d_ws, size_t ws_size,
                              hipStream_t stream)
{
    (void)in_sizes; (void)n_in; (void)out_size; (void)ws_size;
    const float* x     = (const float*)d_in[0];   // (4,2048,768)
    const float* w_qkv = (const float*)d_in[1];   // (2304,768)
    const float* w_out = (const float*)d_in[2];   // (768,768)
    float* out = (float*)d_out;                   // (4,2048,768)

    ushort* xb    = (ushort*)d_ws;                // bf16 x [8192][768]
    ushort* wqkvb = xb + QS_;                     // bf16 [2304][768]
    ushort* woutb = wqkvb + (size_t)3 * C_ * C_;  // bf16 [768][768]
    ushort* qb    = woutb + (size_t)C_ * C_;      // bf16 [bh][t][d], pre-scaled
    ushort* kb    = qb + QS_;                     // bf16 [bh][t][d]
    ushort* vb    = kb + QS_;                     // bf16 [bh][d][t] (transposed)
    ushort* ob    = vb + QS_;                     // bf16 [b][t][h*64+d]

    // [0] fp32 -> bf16 converts (one launch).
    cvt_all<<<8448, 256, 0, stream>>>((const float4*)x, (const float4*)w_qkv,
                                      (const float4*)w_out, (ushort4*)xb,
                                      (ushort4*)wqkvb, (ushort4*)woutb);

    // [1] qkv projection (MFMA) + bf16 scatter. M=8192, N=2304, K=768.
    mgemm<1><<<dim3(18, 64), 256, 0, stream>>>(xb, wqkvb, nullptr, C_, 0, qb, kb, vb);

    // [2] RoPE in place on q, k.
    rope_kernel<<<6144, 256, 0, stream>>>(qb, kb);

    // [3] causal flash attention (bf16 MFMA, paired q-tiles).
    flash_mfma<<<dim3(16, BH_), 256, 0, stream>>>(qb, kb, vb, ob);

    // [4] output projection (MFMA, fp32 store). M=8192, N=768, K=768.
    mgemm<0><<<dim3(6, 64), 256, 0, stream>>>(ob, woutb, out, C_, C_,
                                              nullptr, nullptr, nullptr);
}

// Round 9
// 246.110 us; speedup vs baseline: 7.3806x; 1.0650x over previous
//
#include <hip/hip_runtime.h>
#include <hip/hip_bf16.h>
#include <math.h>

// Fused causal attention block — all matmuls on bf16 MFMA.
// [0] cvt: x, w_qkv, w_out fp32 -> bf16 (single kernel)
// [1] qkv = x @ w_qkv^T  (MFMA GEMM; epilogue: bf16 q/k [bh][t][d] with
//     RoPE fused (fp32 domain, shfl_xor(8) partner), q pre-scaled by
//     0.125*log2e for exp2 softmax, V^T bf16 [bh][d][t])
// [3] causal flash attention via mfma_f32_16x16x32_bf16 -> bf16 o
//     r9: VALU diet — defer-max (T13, rescale only when row max grows >8),
//     per-lane partial l reduced once in epilogue, HW bf16 converts.
// [4] out = o @ w_out^T (MFMA GEMM, fp32 store)

namespace {

constexpr int B_ = 4, T_ = 2048, C_ = 768, NH_ = 12, HD_ = 64;
constexpr int BH_ = B_ * NH_;                  // 48
constexpr size_t QS_ = (size_t)BH_ * T_ * HD_; // 6291456 elems / tensor

typedef short short8 __attribute__((ext_vector_type(8)));  // 8 bf16 = 4 VGPR
typedef float f32x4 __attribute__((ext_vector_type(4)));

__device__ inline ushort f2bf(float f) {           // RNE via HW cvt (m240)
    return __builtin_bit_cast(ushort, __float2bfloat16(f));
}

// ---------------- fp32 -> bf16 convert, all three tensors in one launch
__global__ __launch_bounds__(256) void cvt_all(
    const float4* __restrict__ x, const float4* __restrict__ wq,
    const float4* __restrict__ wo, ushort4* __restrict__ xb,
    ushort4* __restrict__ wqb, ushort4* __restrict__ wob)
{
    int i = blockIdx.x * 256 + threadIdx.x;
    const float4* s; ushort4* d;
    if (i < 1572864) { s = x; d = xb; }
    else if (i < 2015232) { s = wq; d = wqb; i -= 1572864; }
    else { s = wo; d = wob; i -= 2015232; if (i >= 147456) return; }
    const float4 v = s[i];
    ushort4 u;
    u.x = f2bf(v.x); u.y = f2bf(v.y); u.z = f2bf(v.z); u.w = f2bf(v.w);
    d[i] = u;
}

// ---------------- bf16 MFMA "NT" GEMM: out[m][n] = sum_k A[m][k]*Bw[n][k]
// m97 structure: 128x128 tile, BK=32, 4 waves, 4x4 f32x4 acc/wave,
// linear LDS via global_load_lds width=16, 2-barrier K-loop.
// EPI==1: scatter bf16 q/k ([t][d], q*scale, RoPE fused) + V^T ([d][t]).
template <int EPI>
__global__ __launch_bounds__(256) void mgemm(
    const ushort* __restrict__ A, const ushort* __restrict__ Bw,
    float* __restrict__ out, int K, int N_,
    ushort* __restrict__ qb, ushort* __restrict__ kb, ushort* __restrict__ vb)
{
    constexpr int BM = 128, BN = 128, BK = 32;
    __shared__ ushort As[BM * BK];   // [128][32] row-major (k-contig)
    __shared__ ushort Bs[BN * BK];

    const int tid = threadIdx.x;
    const int w = tid >> 6, l = tid & 63;
    const int lg = l >> 4, lc = l & 15;
    const int wr = w >> 1, wc = w & 1;         // wave -> 64x64 quadrant
    const int m0 = blockIdx.y * BM;
    const int n0 = blockIdx.x * BN;

    f32x4 acc[4][4] = {};

    for (int k0 = 0; k0 < K; k0 += BK) {
#pragma unroll
        for (int i = 0; i < 2; ++i) {
            const int cb = w * 128 + i * 64;   // wave-uniform chunk base
            const int c = cb + l;
            const ushort* ga = &A[(size_t)(m0 + (c >> 2)) * K + k0 + (c & 3) * 8];
            const ushort* gb = &Bw[(size_t)(n0 + (c >> 2)) * K + k0 + (c & 3) * 8];
            __builtin_amdgcn_global_load_lds(
                (const __attribute__((address_space(1))) void*)ga,
                (__attribute__((address_space(3))) void*)&As[(size_t)cb * 8], 16, 0, 0);
            __builtin_amdgcn_global_load_lds(
                (const __attribute__((address_space(1))) void*)gb,
                (__attribute__((address_space(3))) void*)&Bs[(size_t)cb * 8], 16, 0, 0);
        }
        __syncthreads();

        short8 af[4], bf[4];
#pragma unroll
        for (int mi = 0; mi < 4; ++mi)
            af[mi] = *(const short8*)&As[(wr * 64 + mi * 16 + lc) * 32 + lg * 8];
#pragma unroll
        for (int nj = 0; nj < 4; ++nj)
            bf[nj] = *(const short8*)&Bs[(wc * 64 + nj * 16 + lc) * 32 + lg * 8];
#pragma unroll
        for (int mi = 0; mi < 4; ++mi)
#pragma unroll
            for (int nj = 0; nj < 4; ++nj)
                acc[mi][nj] = __builtin_amdgcn_mfma_f32_16x16x32_bf16(
                    af[mi], bf[nj], acc[mi][nj], 0, 0, 0);
        __syncthreads();
    }

    // C/D layout: col = lane&15, row = (lane>>4)*4 + reg
    if constexpr (EPI == 0) {
        (void)qb; (void)kb; (void)vb;
#pragma unroll
        for (int mi = 0; mi < 4; ++mi) {
            const int m = m0 + wr * 64 + mi * 16 + lg * 4;
#pragma unroll
            for (int nj = 0; nj < 4; ++nj) {
                const int n = n0 + wc * 64 + nj * 16 + lc;
#pragma unroll
                for (int r = 0; r < 4; ++r)
                    out[(size_t)(m + r) * N_ + n] = acc[mi][nj][r];
            }
        }
    } else {
        (void)out; (void)N_;
#pragma unroll
        for (int mi = 0; mi < 4; ++mi) {
            const int m = m0 + wr * 64 + mi * 16 + lg * 4;   // row of reg 0
            const int b = m >> 11, t0 = m & (T_ - 1);        // same b for r=0..3
#pragma unroll
            for (int nj = 0; nj < 4; ++nj) {
                const int n = n0 + wc * 64 + nj * 16 + lc;   // [0, 2304)
                const int sec = n / C_;                      // 0=q 1=k 2=v
                const int cc = n - sec * C_;
                const int h = cc >> 6, di = cc & 63;         // wave-uniform h,sec
                if (sec == 2) {                              // V^T [d][t], t consec
                    ushort4 w4;
                    w4.x = f2bf(acc[mi][nj][0]); w4.y = f2bf(acc[mi][nj][1]);
                    w4.z = f2bf(acc[mi][nj][2]); w4.w = f2bf(acc[mi][nj][3]);
                    *(ushort4*)&vb[((size_t)(b * NH_ + h) * HD_ + di) * T_ + t0] = w4;
                } else {
                    ushort* dst = (sec == 0) ? qb : kb;
                    // q scale = 1/sqrt(64) * log2(e): exp2-softmax pre-fold
                    const float sfac = (sec == 0) ? 0.18033688f : 1.f;
                    float vals[4];
#pragma unroll
                    for (int r = 0; r < 4; ++r) vals[r] = acc[mi][nj][r] * sfac;
                    if (di < 16) {   // RoPE columns; wave-uniform branch
                        // pair (i, i+8): partner lives 8 lanes away (di^8)
                        const float fr =
                            __expf(-(float)(lc & 7) * 1.15129254649702f);
#pragma unroll
                        for (int r = 0; r < 4; ++r) {
                            const float part = __shfl_xor(vals[r], 8);
                            const float ang = (float)(t0 + r) * fr;
                            const float cs = cosf(ang), sn = sinf(ang);
                            vals[r] = (di < 8) ? vals[r] * cs - part * sn
                                               : vals[r] * cs + part * sn;
                        }
                    }
#pragma unroll
                    for (int r = 0; r < 4; ++r)
                        dst[((size_t)(b * NH_ + h) * T_ + t0 + r) * HD_ + di] =
                            f2bf(vals[r]);
                }
            }
        }
    }
}

// ---------------- causal flash attention via bf16 MFMA.
// Block = 4 waves, q-tiles {j, 31-j}: 33 tile-iters for EVERY block.
// Grid (16, 48) = 768 blocks = 3/CU, deterministic balance.
// K/V double-buffered (stage(next) after barrier, overlaps compute).
// r9: defer-max softmax (m starts 0, exp2 domain, rescale only if a row
// max grows by >8 — P bounded by 2^8, fp32 accum safe), per-lane partial
// l reduced once in epilogue, HW bf16 converts.
__global__ __launch_bounds__(256) void flash_mfma(
    const ushort* __restrict__ q, const ushort* __restrict__ k,
    const ushort* __restrict__ v, ushort* __restrict__ o)
{
    __shared__ ushort Ks[2][64 * 64];
    __shared__ ushort Vs[2][64 * 64];
    __shared__ ushort Ps[4][16 * 64];

    const int j = blockIdx.x;                     // 0..15
    const int bh = blockIdx.y;
    const int b = bh / NH_, h = bh % NH_;
    const int tid = threadIdx.x;
    const int w = tid >> 6, l = tid & 63;
    const int lg = l >> 4, lc = l & 15;

    const size_t kvbase = (size_t)bh * T_ * HD_;   // q,k: [t][d]
    const size_t vbase  = (size_t)bh * HD_ * T_;   // v:   [d][t]

    // stage K+V tile t0 into buffer buf: linear LDS dest, XOR swizzle
    // pre-applied to the GLOBAL source column (rule 21).
    auto stage = [&](int buf, int t0) {
#pragma unroll
        for (int i = 0; i < 2; ++i) {
            const int cb = (w * 2 + i) * 64;      // wave-uniform chunk base
            const int c = cb + l;
            const int row = c >> 3, s8 = (c & 7) * 8;
            const int col = s8 ^ ((row & 7) << 3);
            __builtin_amdgcn_global_load_lds(
                (const __attribute__((address_space(1))) void*)
                    &k[kvbase + (size_t)(t0 + row) * HD_ + col],
                (__attribute__((address_space(3))) void*)&Ks[buf][cb * 8], 16, 0, 0);
            __builtin_amdgcn_global_load_lds(
                (const __attribute__((address_space(1))) void*)
                    &v[vbase + (size_t)row * T_ + t0 + col],
                (__attribute__((address_space(3))) void*)&Vs[buf][cb * 8], 16, 0, 0);
        }
    };

    int cur = 0;
    stage(0, 0);                                   // prologue: seg0 tile0

    for (int seg = 0; seg < 2; ++seg) {
        const int qi = seg ? (31 - j) : j;
        const int q0 = qi * 64;

        short8 aq[2];
        {
            const ushort* qp =
                q + kvbase + (size_t)(q0 + w * 16 + lc) * HD_ + lg * 8;
            aq[0] = *(const short8*)(qp);
            aq[1] = *(const short8*)(qp + 32);
        }
        f32x4 oa[4] = {};
        float m[4] = {0.f, 0.f, 0.f, 0.f};         // deferred max (log2 units)
        float lr[4] = {0.f, 0.f, 0.f, 0.f};        // per-lane PARTIAL denoms

        const int nkt = qi + 1;
        for (int t0i = 0; t0i < nkt; ++t0i) {
            const int t0 = t0i * 64;
            __syncthreads();     // prefetch landed + prev reads done
            const bool lastAll = (seg == 1) && (t0i == nkt - 1);
            if (!lastAll) {
                const int nt0 = (t0i + 1 < nkt) ? (t0 + 64) : 0;  // next seg wraps
                stage(cur ^ 1, nt0);
            }

            f32x4 sa[4];
            __builtin_amdgcn_s_setprio(1);
#pragma unroll
            for (int kc = 0; kc < 4; ++kc) {
                const int row = kc * 16 + lc;
                const int base = row * 64;
                const int sw = (row & 7) << 3;
                short8 b0 = *(const short8*)&Ks[cur][(base + lg * 8) ^ sw];
                short8 b1 = *(const short8*)&Ks[cur][(base + 32 + lg * 8) ^ sw];
                f32x4 z = {0.f, 0.f, 0.f, 0.f};
                z = __builtin_amdgcn_mfma_f32_16x16x32_bf16(aq[0], b0, z, 0, 0, 0);
                z = __builtin_amdgcn_mfma_f32_16x16x32_bf16(aq[1], b1, z, 0, 0, 0);
                sa[kc] = z;
            }
            __builtin_amdgcn_s_setprio(0);

            if (t0 + 63 > q0 + w * 16) {              // causal mask (diag only)
#pragma unroll
                for (int kc = 0; kc < 4; ++kc) {
                    const int kg = t0 + kc * 16 + lc;
#pragma unroll
                    for (int r = 0; r < 4; ++r) {
                        const int qg = q0 + w * 16 + lg * 4 + r;
                        if (kg > qg) sa[kc][r] = -1e30f;
                    }
                }
            }

            // defer-max check: common path has NO rescale, NO shuffles.
            float pr[4];
#pragma unroll
            for (int r = 0; r < 4; ++r)
                pr[r] = fmaxf(fmaxf(sa[0][r], sa[1][r]),
                              fmaxf(sa[2][r], sa[3][r]));
            const bool ok = (pr[0] <= m[0] + 8.f) & (pr[1] <= m[1] + 8.f) &
                            (pr[2] <= m[2] + 8.f) & (pr[3] <= m[3] + 8.f);
            if (!__all(ok)) {                         // rare: real rescale
#pragma unroll
                for (int r = 0; r < 4; ++r) {
                    float a = pr[r];
                    a = fmaxf(a, __shfl_xor(a, 1));
                    a = fmaxf(a, __shfl_xor(a, 2));
                    a = fmaxf(a, __shfl_xor(a, 4));
                    a = fmaxf(a, __shfl_xor(a, 8));
                    const float mn = fmaxf(m[r], a);
                    const float sc = exp2f(m[r] - mn);
                    lr[r] *= sc;
                    oa[0][r] *= sc; oa[1][r] *= sc;
                    oa[2][r] *= sc; oa[3][r] *= sc;
                    m[r] = mn;
                }
            }

            // P-gen: p = 2^(s - m), accumulate per-lane partial denom.
#pragma unroll
            for (int kc = 0; kc < 4; ++kc) {
#pragma unroll
                for (int r = 0; r < 4; ++r) {
                    const float p = exp2f(sa[kc][r] - m[r]);   // masked -> 0
                    lr[r] += p;
                    const int qr = lg * 4 + r;
                    Ps[w][(qr * 64 + kc * 16 + lc) ^ ((qr & 7) << 3)] = f2bf(p);
                }
            }

            short8 pa[2];
            {
                const int sw = (lc & 7) << 3;
                pa[0] = *(const short8*)&Ps[w][(lc * 64 + lg * 8) ^ sw];
                pa[1] = *(const short8*)&Ps[w][(lc * 64 + 32 + lg * 8) ^ sw];
            }
            __builtin_amdgcn_s_setprio(1);
#pragma unroll
            for (int dc = 0; dc < 4; ++dc) {
                const int row = dc * 16 + lc;
                const int base = row * 64;
                const int sw = (row & 7) << 3;
                short8 b0 = *(const short8*)&Vs[cur][(base + lg * 8) ^ sw];
                short8 b1 = *(const short8*)&Vs[cur][(base + 32 + lg * 8) ^ sw];
                oa[dc] = __builtin_amdgcn_mfma_f32_16x16x32_bf16(pa[0], b0, oa[dc], 0, 0, 0);
                oa[dc] = __builtin_amdgcn_mfma_f32_16x16x32_bf16(pa[1], b1, oa[dc], 0, 0, 0);
            }
            __builtin_amdgcn_s_setprio(0);
            cur ^= 1;
        }

        // epilogue: reduce partial l across the 16-lane row group, divide.
#pragma unroll
        for (int r = 0; r < 4; ++r) {
            float a = lr[r];
            a += __shfl_xor(a, 1); a += __shfl_xor(a, 2);
            a += __shfl_xor(a, 4); a += __shfl_xor(a, 8);
            const float inv = 1.f / a;
            const int qg = q0 + w * 16 + lg * 4 + r;
            ushort* op = o + (size_t)(b * T_ + qg) * C_ + h * HD_ + lc;
#pragma unroll
            for (int dc = 0; dc < 4; ++dc) op[dc * 16] = f2bf(oa[dc][r] * inv);
        }
    }
}

}  // namespace

extern "C" void kernel_launch(void* const* d_in, const int* in_sizes, int n_in,
                              void* d_out, int out_size, void* d_ws, size_t ws_size,
                              hipStream_t stream)
{
    (void)in_sizes; (void)n_in; (void)out_size; (void)ws_size;
    const float* x     = (const float*)d_in[0];   // (4,2048,768)
    const float* w_qkv = (const float*)d_in[1];   // (2304,768)
    const float* w_out = (const float*)d_in[2];   // (768,768)
    float* out = (float*)d_out;                   // (4,2048,768)

    ushort* xb    = (ushort*)d_ws;                // bf16 x [8192][768]
    ushort* wqkvb = xb + QS_;                     // bf16 [2304][768]
    ushort* woutb = wqkvb + (size_t)3 * C_ * C_;  // bf16 [768][768]
    ushort* qb    = woutb + (size_t)C_ * C_;      // bf16 [bh][t][d], scaled+roped
    ushort* kb    = qb + QS_;                     // bf16 [bh][t][d], roped
    ushort* vb    = kb + QS_;                     // bf16 [bh][d][t] (transposed)
    ushort* ob    = vb + QS_;                     // bf16 [b][t][h*64+d]

    // [0] fp32 -> bf16 converts (one launch).
    cvt_all<<<8448, 256, 0, stream>>>((const float4*)x, (const float4*)w_qkv,
                                      (const float4*)w_out, (ushort4*)xb,
                                      (ushort4*)wqkvb, (ushort4*)woutb);

    // [1] qkv projection (MFMA) + bf16 scatter + fused RoPE. M=8192, N=2304.
    mgemm<1><<<dim3(18, 64), 256, 0, stream>>>(xb, wqkvb, nullptr, C_, 0, qb, kb, vb);

    // [3] causal flash attention (bf16 MFMA, paired q-tiles).
    flash_mfma<<<dim3(16, BH_), 256, 0, stream>>>(qb, kb, vb, ob);

    // [4] output projection (MFMA, fp32 store). M=8192, N=768, K=768.
    mgemm<0><<<dim3(6, 64), 256, 0, stream>>>(ob, woutb, out, C_, C_,
                                              nullptr, nullptr, nullptr);
}